// Round 2
// baseline (855.716 us; speedup 1.0000x reference)
//
#include <hip/hip_runtime.h>
#include <hip/hip_bf16.h>

#define D_FEAT 64
#define OVF_CAP 65536
#define EB 4096              // edges per scatter block
#define NBMAX 1024           // max coarse buckets (n <= 256K)

typedef unsigned int uint32;

__device__ inline float blo(uint32 u) { return __uint_as_float(u << 16); }
__device__ inline float bhi(uint32 u) { return __uint_as_float(u & 0xffff0000u); }
__device__ inline float dinv(int d) { return (d > 0) ? rsqrtf((float)d) : 0.0f; }

// ---- phase 1 (fused): LDS bucket histogram -> segment reservation -> edge
//      placement; exact per-node degree via global atomics; bf16 cast of x.
//      Replaces the old hist/colscan/tinyscan/scat3 quartet.
__global__ __launch_bounds__(256) void k_scatter(const int* __restrict__ row,
                                                 const int* __restrict__ col,
                                                 const float2* __restrict__ x2,
                                                 uint32* __restrict__ xb,
                                                 int* __restrict__ deg,
                                                 int* __restrict__ cursor,
                                                 uint32* __restrict__ binned,
                                                 int2* __restrict__ ovf,
                                                 int* __restrict__ ovf_cnt,
                                                 int nhalf, int E, int nb, int CAP) {
    __shared__ int h[NBMAX];
    for (int i = threadIdx.x; i < nb; i += 256) h[i] = 0;
    __syncthreads();
    const int s = blockIdx.x * EB;
    const int e = (s + EB < E) ? s + EB : E;
    // pass 1: bucket histogram + exact degree
    for (int i = s + threadIdx.x; i < e; i += 256) {
        int c = col[i];
        atomicAdd(&h[c >> 8], 1);
        atomicAdd(&deg[c], 1);
    }
    __syncthreads();
    // reserve one contiguous slice per non-empty bucket (global atomic)
    for (int k = threadIdx.x; k < nb; k += 256) {
        int c = h[k];
        if (c) h[k] = atomicAdd(&cursor[k], c);   // h[k] := within-bucket base
    }
    __syncthreads();
    // pass 2: place edges (col re-read is L1/L2-hot)
    for (int i = s + threadIdx.x; i < e; i += 256) {
        int c = col[i];
        uint32 r = (uint32)row[i];
        int b = c >> 8;
        int pos = atomicAdd(&h[b], 1);            // LDS cursor from base
        if (pos < CAP) {
            binned[(size_t)b * CAP + pos] = (r << 8) | (uint32)(c & 255);
        } else {
            int o = atomicAdd(ovf_cnt, 1);
            if (o < OVF_CAP) ovf[o] = make_int2((int)r, c);
        }
    }
    // fused bf16 cast, node-major linear (xb[node] = 32 contiguous uint32)
    const int t = blockIdx.x * 256 + threadIdx.x;
    const int stride = gridDim.x * 256;
    for (int j = t; j < nhalf; j += stride) {
        float2 v = x2[j];
        __hip_bfloat16 bx = __float2bfloat16(v.x);
        __hip_bfloat16 by = __float2bfloat16(v.y);
        uint32 ux = *reinterpret_cast<unsigned short*>(&bx);
        uint32 uy = *reinterpret_cast<unsigned short*>(&by);
        xb[j] = ux | (uy << 16);
    }
}

// ---- phase 2 (fused): per-bucket LDS f32 accumulator gather + epilogue.
//      Replaces k_build + slots + k_gather4. One block per 256-node bucket,
//      64KB LDS accum; 32-lane groups, one edge per group, 2-deep unroll.
__global__ __launch_bounds__(1024) void k_bucket(const uint32* __restrict__ binned,
                                                 const int* __restrict__ cursor,
                                                 const uint32* __restrict__ xb,
                                                 const int* __restrict__ deg,
                                                 const float4* __restrict__ x4,
                                                 const float* __restrict__ alpha_p,
                                                 const float* __restrict__ rs_p,
                                                 float4* __restrict__ out4,
                                                 int n, int CAP) {
    __shared__ float acc[256 * D_FEAT];           // 64 KB
    // zero
    for (int i = threadIdx.x; i < 256 * D_FEAT / 4; i += 1024)
        *reinterpret_cast<float4*>(&acc[i * 4]) = make_float4(0.f, 0.f, 0.f, 0.f);
    __syncthreads();

    const int k = blockIdx.x;
    int cnt = cursor[k];
    if (cnt > CAP) cnt = CAP;
    const uint32* seg = binned + (size_t)k * CAP;

    const int g = threadIdx.x >> 5;               // 32 groups of 32 lanes
    const int l = threadIdx.x & 31;               // lane -> feats 2l, 2l+1

    int i = g;
    for (; i + 32 < cnt; i += 64) {               // 2 edges in flight per group
        uint32 pa = seg[i];
        uint32 pb = seg[i + 32];
        int ra = (int)(pa >> 8), ca = (int)(pa & 255);
        int rb = (int)(pb >> 8), cb = (int)(pb & 255);
        int da = deg[ra], db = deg[rb];
        uint32 ua = xb[(size_t)ra * 32 + l];      // 32 lanes x 4B = 128B row
        uint32 ub = xb[(size_t)rb * 32 + l];
        float wa = dinv(da), wb = dinv(db);
        atomicAdd(&acc[ca * D_FEAT + 2 * l],     wa * blo(ua));
        atomicAdd(&acc[ca * D_FEAT + 2 * l + 1], wa * bhi(ua));
        atomicAdd(&acc[cb * D_FEAT + 2 * l],     wb * blo(ub));
        atomicAdd(&acc[cb * D_FEAT + 2 * l + 1], wb * bhi(ub));
    }
    for (; i < cnt; i += 32) {                    // tail (<= 2 iterations)
        uint32 pa = seg[i];
        int ra = (int)(pa >> 8), ca = (int)(pa & 255);
        float wa = dinv(deg[ra]);
        uint32 ua = xb[(size_t)ra * 32 + l];
        atomicAdd(&acc[ca * D_FEAT + 2 * l],     wa * blo(ua));
        atomicAdd(&acc[ca * D_FEAT + 2 * l + 1], wa * bhi(ua));
    }
    __syncthreads();

    // epilogue: out = alpha * dinv(deg) * acc + rs * x   (streamed)
    const float alpha = *alpha_p;
    const float rs = *rs_p;
    const int base = k << 8;
    for (int idx = threadIdx.x; idx < 256 * 16; idx += 1024) {
        int nl = idx >> 4;                        // node within bucket
        int l4 = idx & 15;                        // float4 index within row
        int node = base + nl;
        if (node >= n) continue;
        float sc = alpha * dinv(deg[node]);
        float4 a = *reinterpret_cast<float4*>(&acc[nl * D_FEAT + l4 * 4]);
        float4 xr = x4[(size_t)node * 16 + l4];
        float4 o;
        o.x = fmaf(sc, a.x, rs * xr.x);
        o.y = fmaf(sc, a.y, rs * xr.y);
        o.z = fmaf(sc, a.z, rs * xr.z);
        o.w = fmaf(sc, a.w, rs * xr.w);
        out4[(size_t)node * 16 + l4] = o;
    }
}

// ---- spill fix-up (empty for uniform inputs): fp32 exact ----
__global__ void k_ovf(const int2* __restrict__ ovf, const int* __restrict__ cnt_p,
                      const float* __restrict__ x, const int* __restrict__ deg,
                      const float* __restrict__ alpha_p, float* __restrict__ out) {
    int cnt = *cnt_p;
    if (cnt > OVF_CAP) cnt = OVF_CAP;
    if (cnt <= 0) return;
    float a = *alpha_p;
    long long total = (long long)cnt * 64;
    long long stride = (long long)gridDim.x * blockDim.x;
    for (long long idx = blockIdx.x * (long long)blockDim.x + threadIdx.x;
         idx < total; idx += stride) {
        int e = (int)(idx >> 6);
        int f = (int)(idx & 63);
        int2 rc = ovf[e];
        float w = a * dinv(deg[rc.x]) * dinv(deg[rc.y]);
        atomicAdd(&out[(size_t)rc.y * D_FEAT + f], w * x[(size_t)rc.x * D_FEAT + f]);
    }
}

// ================= fallback: direct padded-CSR build + node-wave gather ======
__global__ void k_prep(const float2* __restrict__ x2, uint32* __restrict__ xb,
                       const int* __restrict__ row, const int* __restrict__ col,
                       int* __restrict__ deg, int* __restrict__ slots,
                       int2* __restrict__ ovf, int* __restrict__ ovf_cnt,
                       int nhalf, int E, int C) {
    int t = blockIdx.x * blockDim.x + threadIdx.x;
    if (t < E) {
        int c = col[t];
        int r = row[t];
        int rk = atomicAdd(&deg[c], 1);
        if (rk < C) {
            slots[(size_t)c * C + rk] = r;
        } else {
            int o = atomicAdd(ovf_cnt, 1);
            if (o < OVF_CAP) ovf[o] = make_int2(r, c);
        }
    }
    const int stride = gridDim.x * blockDim.x;
    for (int j = t; j < nhalf; j += stride) {
        float2 v = x2[j];
        __hip_bfloat16 bx = __float2bfloat16(v.x);
        __hip_bfloat16 by = __float2bfloat16(v.y);
        uint32 ux = *reinterpret_cast<unsigned short*>(&bx);
        uint32 uy = *reinterpret_cast<unsigned short*>(&by);
        xb[j] = ux | (uy << 16);
    }
}

__global__ void k_gather4(const uint32* __restrict__ xb,
                          const float4* __restrict__ x4,
                          const int* __restrict__ deg,
                          const int* __restrict__ slots,
                          const float* __restrict__ alpha_p,
                          const float* __restrict__ rs_p,
                          float4* __restrict__ out4, int n, int C) {
    int wid = (blockIdx.x * blockDim.x + threadIdx.x) >> 6;
    if (wid >= n) return;
    const int lane = threadIdx.x & 63;
    const int q = lane >> 4;
    const int l = lane & 15;
    int d = deg[wid];
    int e = (d < C) ? d : C;
    const int* sl = slots + (size_t)wid * C;
    float ax = 0.f, ay = 0.f, az = 0.f, aw = 0.f;
    int k = 0;
    for (; k + 16 <= e; k += 16) {
        int s0 = sl[k + q];
        int s1 = sl[k + 4 + q];
        int s2 = sl[k + 8 + q];
        int s3 = sl[k + 12 + q];
        int d0 = deg[s0], d1 = deg[s1], d2 = deg[s2], d3 = deg[s3];
        uint2 p0 = ((const uint2*)(xb + (size_t)s0 * 32))[l];
        uint2 p1 = ((const uint2*)(xb + (size_t)s1 * 32))[l];
        uint2 p2 = ((const uint2*)(xb + (size_t)s2 * 32))[l];
        uint2 p3 = ((const uint2*)(xb + (size_t)s3 * 32))[l];
        float w0 = dinv(d0), w1 = dinv(d1), w2 = dinv(d2), w3 = dinv(d3);
        ax = fmaf(w0, blo(p0.x), ax); ay = fmaf(w0, bhi(p0.x), ay);
        az = fmaf(w0, blo(p0.y), az); aw = fmaf(w0, bhi(p0.y), aw);
        ax = fmaf(w1, blo(p1.x), ax); ay = fmaf(w1, bhi(p1.x), ay);
        az = fmaf(w1, blo(p1.y), az); aw = fmaf(w1, bhi(p1.y), aw);
        ax = fmaf(w2, blo(p2.x), ax); ay = fmaf(w2, bhi(p2.x), ay);
        az = fmaf(w2, blo(p2.y), az); aw = fmaf(w2, bhi(p2.y), aw);
        ax = fmaf(w3, blo(p3.x), ax); ay = fmaf(w3, bhi(p3.x), ay);
        az = fmaf(w3, blo(p3.y), az); aw = fmaf(w3, bhi(p3.y), aw);
    }
    for (; k < e; k += 4) {
        int kk = k + q;
        if (kk < e) {
            int s0 = sl[kk];
            float w0 = dinv(deg[s0]);
            uint2 p0 = ((const uint2*)(xb + (size_t)s0 * 32))[l];
            ax = fmaf(w0, blo(p0.x), ax); ay = fmaf(w0, bhi(p0.x), ay);
            az = fmaf(w0, blo(p0.y), az); aw = fmaf(w0, bhi(p0.y), aw);
        }
    }
    ax += __shfl_down(ax, 32, 64); ay += __shfl_down(ay, 32, 64);
    az += __shfl_down(az, 32, 64); aw += __shfl_down(aw, 32, 64);
    ax += __shfl_down(ax, 16, 64); ay += __shfl_down(ay, 16, 64);
    az += __shfl_down(az, 16, 64); aw += __shfl_down(aw, 16, 64);
    if (q == 0) {
        float adw = (*alpha_p) * dinv(d);
        float rs  = *rs_p;
        float4 xr = x4[(size_t)wid * 16 + l];
        float4 o;
        o.x = fmaf(adw, ax, rs * xr.x);
        o.y = fmaf(adw, ay, rs * xr.y);
        o.z = fmaf(adw, az, rs * xr.z);
        o.w = fmaf(adw, aw, rs * xr.w);
        out4[(size_t)wid * 16 + l] = o;
    }
}

static inline char* align_up(char* p, size_t a) {
    return (char*)(((uintptr_t)p + (a - 1)) & ~(uintptr_t)(a - 1));
}

extern "C" void kernel_launch(void* const* d_in, const int* in_sizes, int n_in,
                              void* d_out, int out_size, void* d_ws, size_t ws_size,
                              hipStream_t stream) {
    const float* x         = (const float*)d_in[0];
    const float* alpha     = (const float*)d_in[1];
    const float* res_scale = (const float*)d_in[2];
    const int*   ei        = (const int*)d_in[3];

    const int n = in_sizes[0] / D_FEAT;      // 100000
    const int E = in_sizes[3] / 2;           // 1600000
    const int* row = ei;                     // sources
    const int* col = ei + E;                 // targets

    float* out = (float*)d_out;
    const int nhalf = n * (D_FEAT / 2);
    const int nb = (n + 255) >> 8;           // coarse buckets (256 nodes each)
    const int B  = (E + EB - 1) / EB;        // scatter blocks

    // ---------- fused reservation-multisplit + bucket-LDS gather ----------
    {
        char* p = (char*)d_ws;
        int*    deg     = (int*)p;            p += (size_t)n * 4;
        int*    cursor  = (int*)p;            p += (size_t)nb * 4;
        int*    ovf_cnt = (int*)p;            p += 4;
        int2*   ovf     = (int2*)p;           p += (size_t)OVF_CAP * 8;
        p = align_up(p, 16);
        uint32* xb      = (uint32*)p;         p += (size_t)n * 128;
        uint32* binned  = (uint32*)p;
        const size_t fixed = (size_t)((char*)binned - (char*)d_ws);

        int CAP = 0;
        if (ws_size > fixed) {
            size_t cap_avail = (ws_size - fixed) / ((size_t)nb * 4);
            CAP = (cap_avail > 8192) ? 8192 : (int)cap_avail;
            CAP &= ~63;                       // keep segments 256B-aligned
        }
        const bool ok = (CAP >= 6144) && (nb <= NBMAX) && (n <= (NBMAX << 8));
        if (ok) {
            // zero deg + cursor + ovf_cnt in one contiguous memset
            hipMemsetAsync(deg, 0, (size_t)(n + nb + 1) * 4, stream);
            k_scatter<<<B, 256, 0, stream>>>(row, col, (const float2*)x, xb,
                                             deg, cursor, binned, ovf, ovf_cnt,
                                             nhalf, E, nb, CAP);
            k_bucket<<<nb, 1024, 0, stream>>>(binned, cursor, xb, deg,
                                              (const float4*)x, alpha, res_scale,
                                              (float4*)out, n, CAP);
            k_ovf<<<64, 256, 0, stream>>>(ovf, ovf_cnt, x, deg, alpha, out);
            return;
        }
    }

    // ---------- fallback: direct padded CSR + node-wave gather ----------
    {
        char* p = (char*)d_ws;
        int*    deg     = (int*)p;            p += (size_t)n * 4;
        int*    ovf_cnt = (int*)p;            p += 4;
        int2*   ovf     = (int2*)p;           p += (size_t)OVF_CAP * 8;
        p = align_up(p, 16);
        uint32* xb      = (uint32*)p;         p += (size_t)n * 128;
        int*    slots   = (int*)p;
        const size_t fixed = (size_t)(p - (char*)d_ws);
        int C = 0;
        if (ws_size > fixed) {
            size_t c_avail = (ws_size - fixed) / ((size_t)n * 4);
            C = (c_avail > 32) ? 32 : (int)c_avail;
        }
        if (C < 1) return;  // ws too small for anything sane
        hipMemsetAsync(deg, 0, (size_t)n * 4 + 4, stream);
        k_prep<<<(E + 255) / 256, 256, 0, stream>>>(
            (const float2*)x, xb, row, col, deg, slots, ovf, ovf_cnt,
            nhalf, E, C);
        const long long tt = (long long)n * D_FEAT;
        const int blocks = (int)((tt + 255) / 256);
        k_gather4<<<blocks, 256, 0, stream>>>(xb, (const float4*)x, deg, slots,
                                              alpha, res_scale, (float4*)out, n, C);
        k_ovf<<<64, 256, 0, stream>>>(ovf, ovf_cnt, x, deg, alpha, out);
    }
}

// Round 3
// 190.017 us; speedup vs baseline: 4.5034x; 4.5034x over previous
//
#include <hip/hip_runtime.h>
#include <hip/hip_bf16.h>

#define D_FEAT 64
#define OVF_CAP 65536
#define EB 4096              // edges per scatter block
#define NBMAX 1024           // max coarse buckets (n <= 256K)

typedef unsigned int uint32;

__device__ inline float blo(uint32 u) { return __uint_as_float(u << 16); }
__device__ inline float bhi(uint32 u) { return __uint_as_float(u & 0xffff0000u); }
__device__ inline float dinv(int d) { return (d > 0) ? rsqrtf((float)d) : 0.0f; }

// ---- phase 1 (fused): LDS bucket histogram -> one global-atomic reservation
//      per (block,bucket) -> edge placement into CAP-padded bucket segments;
//      fused bf16 cast of x. Replaces hist/colscan/tinyscan/scat3.
__global__ __launch_bounds__(256) void k_scatter(const int* __restrict__ row,
                                                 const int* __restrict__ col,
                                                 const float2* __restrict__ x2,
                                                 uint32* __restrict__ xb,
                                                 int* __restrict__ deg,
                                                 int* __restrict__ cursor,
                                                 uint32* __restrict__ binned,
                                                 int2* __restrict__ ovf,
                                                 int* __restrict__ ovf_cnt,
                                                 int nhalf, int E, int nb, int CAP) {
    __shared__ int h[NBMAX];
    for (int i = threadIdx.x; i < nb; i += 256) h[i] = 0;
    __syncthreads();
    const int s = blockIdx.x * EB;
    const int e = (s + EB < E) ? s + EB : E;
    // pass 1: per-block bucket histogram (LDS atomics only)
    for (int i = s + threadIdx.x; i < e; i += 256)
        atomicAdd(&h[col[i] >> 8], 1);
    __syncthreads();
    // reserve one contiguous slice per non-empty bucket (1 global atomic each)
    for (int k = threadIdx.x; k < nb; k += 256) {
        int c = h[k];
        if (c) h[k] = atomicAdd(&cursor[k], c);   // h[k] := within-bucket base
    }
    __syncthreads();
    // pass 2: place edges (col re-read is L1/L2-hot)
    for (int i = s + threadIdx.x; i < e; i += 256) {
        int c = col[i];
        uint32 r = (uint32)row[i];
        int b = c >> 8;
        int pos = atomicAdd(&h[b], 1);            // LDS cursor from reserved base
        if (pos < CAP) {
            binned[(size_t)b * CAP + pos] = (r << 8) | (uint32)(c & 255);
        } else {
            // segment full (pathological skew): count degree here, fix msg later
            atomicAdd(&deg[c], 1);
            int o = atomicAdd(ovf_cnt, 1);
            if (o < OVF_CAP) ovf[o] = make_int2((int)r, c);
        }
    }
    // fused bf16 cast, node-major linear (xb[node] = 32 contiguous uint32)
    const int t = blockIdx.x * 256 + threadIdx.x;
    const int stride = gridDim.x * 256;
    for (int j = t; j < nhalf; j += stride) {
        float2 v = x2[j];
        __hip_bfloat16 bx = __float2bfloat16(v.x);
        __hip_bfloat16 by = __float2bfloat16(v.y);
        uint32 ux = *reinterpret_cast<unsigned short*>(&bx);
        uint32 uy = *reinterpret_cast<unsigned short*>(&by);
        xb[j] = ux | (uy << 16);
    }
}

// ---- phase 2: per-bucket LDS ranks -> padded slots; fused deg + winv output ----
__global__ __launch_bounds__(1024) void k_build(const int* __restrict__ cursor,
                                                const uint32* __restrict__ binned,
                                                int* __restrict__ slots,
                                                int* __restrict__ deg,
                                                float* __restrict__ winv,
                                                int2* __restrict__ ovf,
                                                int* __restrict__ ovf_cnt,
                                                int n, int C, int CAP) {
    __shared__ int cnt[256];
    const int k = blockIdx.x;
    if (threadIdx.x < 256) cnt[threadIdx.x] = 0;
    __syncthreads();
    int tot = cursor[k];
    const int e = (tot < CAP) ? tot : CAP;
    const uint32* seg = binned + (size_t)k * CAP;
    const int base = k << 8;
    for (int i = threadIdx.x; i < e; i += 1024) {
        uint32 pk = seg[i];
        int cl = (int)(pk & 255);
        int r  = (int)(pk >> 8);
        int rk = atomicAdd(&cnt[cl], 1);            // LDS atomic
        int c  = base + cl;
        if (rk < C) {
            slots[(size_t)c * C + rk] = r;          // 32KB block-private window
        } else {
            int o = atomicAdd(ovf_cnt, 1);
            if (o < OVF_CAP) ovf[o] = make_int2(r, c);
        }
    }
    __syncthreads();
    int i = base + threadIdx.x;
    if (threadIdx.x < 256 && i < n) {
        int d = cnt[threadIdx.x] + deg[i];          // + scatter-overflow count
        deg[i] = d;
        winv[i] = dinv(d);
    }
}

// ---- gather: one wave per node, 4 edges in parallel, 16-edge unroll ----
__global__ void k_gather4(const uint32* __restrict__ xb,
                          const float4* __restrict__ x4,
                          const float* __restrict__ winv,
                          const int* __restrict__ slots,
                          const float* __restrict__ alpha_p,
                          const float* __restrict__ rs_p,
                          float4* __restrict__ out4, int n, int C) {
    int wid = (blockIdx.x * blockDim.x + threadIdx.x) >> 6;
    if (wid >= n) return;
    const int lane = threadIdx.x & 63;
    const int q = lane >> 4;
    const int l = lane & 15;
    float wn = winv[wid];
    int d = (int)0;
    // e = min(C, true count in slots): slots holds min(deg, C) entries; recover
    // the count from winv? No -- read it cheaply from the slot-count proxy:
    // we stored exactly min(deg,C) entries; deg reconstruction: 1/winv^2 is
    // lossy, so pass deg via winv table only for weights and read count from
    // the dedicated deg array kept warm in L2.
    (void)d;
    float4 xr = make_float4(0.f, 0.f, 0.f, 0.f);
    if (q == 0) xr = x4[(size_t)wid * 16 + l];      // hoisted residual load
    const int* sl = slots + (size_t)wid * C;
    float ax = 0.f, ay = 0.f, az = 0.f, aw = 0.f;
    int e = (int)__builtin_nontemporal_load(&sl[-1]);  // placeholder never used
    e = 0;  // (kept simple below via degc pointer)
    // NOTE: count comes from degc (see wrapper passing slots=-... ) -- simplest:
    // we re-load from the global deg table bound as the last 4 bytes? To keep
    // this kernel self-contained, count is passed via winv's paired deg array:
    (void)e;
    // --- actual implementation uses degc param below ---
    ax = ax; // no-op
    // (real body in k_gather4d)
    if (q == 0) out4[(size_t)wid * 16 + l] = xr;    // never reached: wrapper uses k_gather4d
}

// real gather (separate to keep deg count + winv weights both available)
__global__ void k_gather4d(const uint32* __restrict__ xb,
                           const float4* __restrict__ x4,
                           const int* __restrict__ deg,
                           const float* __restrict__ winv,
                           const int* __restrict__ slots,
                           const float* __restrict__ alpha_p,
                           const float* __restrict__ rs_p,
                           float4* __restrict__ out4, int n, int C) {
    int wid = (blockIdx.x * blockDim.x + threadIdx.x) >> 6;
    if (wid >= n) return;
    const int lane = threadIdx.x & 63;
    const int q = lane >> 4;
    const int l = lane & 15;
    int d = deg[wid];
    int e = (d < C) ? d : C;
    float4 xr = make_float4(0.f, 0.f, 0.f, 0.f);
    if (q == 0) xr = x4[(size_t)wid * 16 + l];      // hoisted residual load
    const int* sl = slots + (size_t)wid * C;
    float ax = 0.f, ay = 0.f, az = 0.f, aw = 0.f;
    int k = 0;
    for (; k + 16 <= e; k += 16) {
        int s0 = sl[k + q];
        int s1 = sl[k + 4 + q];
        int s2 = sl[k + 8 + q];
        int s3 = sl[k + 12 + q];
        float w0 = winv[s0], w1 = winv[s1], w2 = winv[s2], w3 = winv[s3];
        uint2 p0 = ((const uint2*)(xb + (size_t)s0 * 32))[l];
        uint2 p1 = ((const uint2*)(xb + (size_t)s1 * 32))[l];
        uint2 p2 = ((const uint2*)(xb + (size_t)s2 * 32))[l];
        uint2 p3 = ((const uint2*)(xb + (size_t)s3 * 32))[l];
        ax = fmaf(w0, blo(p0.x), ax); ay = fmaf(w0, bhi(p0.x), ay);
        az = fmaf(w0, blo(p0.y), az); aw = fmaf(w0, bhi(p0.y), aw);
        ax = fmaf(w1, blo(p1.x), ax); ay = fmaf(w1, bhi(p1.x), ay);
        az = fmaf(w1, blo(p1.y), az); aw = fmaf(w1, bhi(p1.y), aw);
        ax = fmaf(w2, blo(p2.x), ax); ay = fmaf(w2, bhi(p2.x), ay);
        az = fmaf(w2, blo(p2.y), az); aw = fmaf(w2, bhi(p2.y), aw);
        ax = fmaf(w3, blo(p3.x), ax); ay = fmaf(w3, bhi(p3.x), ay);
        az = fmaf(w3, blo(p3.y), az); aw = fmaf(w3, bhi(p3.y), aw);
    }
    for (; k < e; k += 4) {
        int kk = k + q;
        if (kk < e) {
            int s0 = sl[kk];
            float w0 = winv[s0];
            uint2 p0 = ((const uint2*)(xb + (size_t)s0 * 32))[l];
            ax = fmaf(w0, blo(p0.x), ax); ay = fmaf(w0, bhi(p0.x), ay);
            az = fmaf(w0, blo(p0.y), az); aw = fmaf(w0, bhi(p0.y), aw);
        }
    }
    ax += __shfl_down(ax, 32, 64); ay += __shfl_down(ay, 32, 64);
    az += __shfl_down(az, 32, 64); aw += __shfl_down(aw, 32, 64);
    ax += __shfl_down(ax, 16, 64); ay += __shfl_down(ay, 16, 64);
    az += __shfl_down(az, 16, 64); aw += __shfl_down(aw, 16, 64);
    if (q == 0) {
        float adw = (*alpha_p) * winv[wid];
        float rs  = *rs_p;
        float4 o;
        o.x = fmaf(adw, ax, rs * xr.x);
        o.y = fmaf(adw, ay, rs * xr.y);
        o.z = fmaf(adw, az, rs * xr.z);
        o.w = fmaf(adw, aw, rs * xr.w);
        out4[(size_t)wid * 16 + l] = o;
    }
}

// ---- overflow fix-up (rare): fp32 exact ----
__global__ void k_ovf(const int2* __restrict__ ovf, const int* __restrict__ cnt_p,
                      const float* __restrict__ x, const float* __restrict__ winv,
                      const float* __restrict__ alpha_p, float* __restrict__ out) {
    int cnt = *cnt_p;
    if (cnt > OVF_CAP) cnt = OVF_CAP;
    if (cnt <= 0) return;
    float a = *alpha_p;
    long long total = (long long)cnt * 64;
    long long stride = (long long)gridDim.x * blockDim.x;
    for (long long idx = blockIdx.x * (long long)blockDim.x + threadIdx.x;
         idx < total; idx += stride) {
        int e = (int)(idx >> 6);
        int f = (int)(idx & 63);
        int2 rc = ovf[e];
        float w = a * winv[rc.x] * winv[rc.y];
        atomicAdd(&out[(size_t)rc.y * D_FEAT + f], w * x[(size_t)rc.x * D_FEAT + f]);
    }
}

// ---- winv table for the fallback path ----
__global__ void k_winv(const int* __restrict__ deg, float* __restrict__ winv, int n) {
    int i = blockIdx.x * blockDim.x + threadIdx.x;
    if (i < n) winv[i] = dinv(deg[i]);
}

// ================= fallback: direct padded-CSR build =================
__global__ void k_prep(const float2* __restrict__ x2, uint32* __restrict__ xb,
                       const int* __restrict__ row, const int* __restrict__ col,
                       int* __restrict__ deg, int* __restrict__ slots,
                       int2* __restrict__ ovf, int* __restrict__ ovf_cnt,
                       int nhalf, int E, int C) {
    int t = blockIdx.x * blockDim.x + threadIdx.x;
    if (t < E) {
        int c = col[t];
        int r = row[t];
        int rk = atomicAdd(&deg[c], 1);
        if (rk < C) {
            slots[(size_t)c * C + rk] = r;
        } else {
            int o = atomicAdd(ovf_cnt, 1);
            if (o < OVF_CAP) ovf[o] = make_int2(r, c);
        }
    }
    const int stride = gridDim.x * blockDim.x;
    for (int j = t; j < nhalf; j += stride) {
        float2 v = x2[j];
        __hip_bfloat16 bx = __float2bfloat16(v.x);
        __hip_bfloat16 by = __float2bfloat16(v.y);
        uint32 ux = *reinterpret_cast<unsigned short*>(&bx);
        uint32 uy = *reinterpret_cast<unsigned short*>(&by);
        xb[j] = ux | (uy << 16);
    }
}

static inline char* align_up(char* p, size_t a) {
    return (char*)(((uintptr_t)p + (a - 1)) & ~(uintptr_t)(a - 1));
}

extern "C" void kernel_launch(void* const* d_in, const int* in_sizes, int n_in,
                              void* d_out, int out_size, void* d_ws, size_t ws_size,
                              hipStream_t stream) {
    const float* x         = (const float*)d_in[0];
    const float* alpha     = (const float*)d_in[1];
    const float* res_scale = (const float*)d_in[2];
    const int*   ei        = (const int*)d_in[3];

    const int n = in_sizes[0] / D_FEAT;      // 100000
    const int E = in_sizes[3] / 2;           // 1600000
    const int* row = ei;                     // sources
    const int* col = ei + E;                 // targets

    float* out = (float*)d_out;
    const int nhalf = n * (D_FEAT / 2);
    const int nb = (n + 255) >> 8;           // coarse buckets (256 nodes each)
    const int B  = (E + EB - 1) / EB;        // scatter blocks

    // ---------- reservation multisplit + padded-CSR + node-wave gather ----------
    {
        char* p = (char*)d_ws;
        int*    deg     = (int*)p;            p += (size_t)n * 4;
        int*    cursor  = (int*)p;            p += (size_t)nb * 4;
        int*    ovf_cnt = (int*)p;            p += 4;
        float*  winv    = (float*)p;          p += (size_t)n * 4;
        int2*   ovf     = (int2*)p;           p += (size_t)OVF_CAP * 8;
        p = align_up(p, 16);
        uint32* xb      = (uint32*)p;         p += (size_t)n * 128;
        uint32* binned  = (uint32*)p;
        const size_t fixed = (size_t)((char*)binned - (char*)d_ws);

        const int C = 32;
        const int mean = (E + nb - 1) / nb;
        int CAP = 0;
        if (ws_size > fixed + (size_t)n * C * 4) {
            long long capb = ((long long)(ws_size - fixed) - (long long)n * C * 4)
                             / ((long long)nb * 4);
            CAP = (capb > 8192) ? 8192 : (int)capb;
            CAP &= ~63;                       // 256B-aligned segments
        }
        const bool ok = (CAP >= mean + 512) && (nb <= NBMAX) && (n <= (NBMAX << 8));
        if (ok) {
            int* slots = (int*)(binned + (size_t)nb * CAP);
            // zero deg + cursor + ovf_cnt (contiguous)
            hipMemsetAsync(deg, 0, (size_t)(n + nb + 1) * 4, stream);
            k_scatter<<<B, 256, 0, stream>>>(row, col, (const float2*)x, xb,
                                             deg, cursor, binned, ovf, ovf_cnt,
                                             nhalf, E, nb, CAP);
            k_build<<<nb, 1024, 0, stream>>>(cursor, binned, slots, deg, winv,
                                             ovf, ovf_cnt, n, C, CAP);
            const long long tt = (long long)n * 64;
            const int blocks = (int)((tt + 255) / 256);
            k_gather4d<<<blocks, 256, 0, stream>>>(xb, (const float4*)x, deg, winv,
                                                   slots, alpha, res_scale,
                                                   (float4*)out, n, C);
            k_ovf<<<64, 256, 0, stream>>>(ovf, ovf_cnt, x, winv, alpha, out);
            return;
        }
    }

    // ---------- fallback: direct padded CSR + node-wave gather ----------
    {
        char* p = (char*)d_ws;
        int*    deg     = (int*)p;            p += (size_t)n * 4;
        int*    ovf_cnt = (int*)p;            p += 4;
        float*  winv    = (float*)p;          p += (size_t)n * 4;
        int2*   ovf     = (int2*)p;           p += (size_t)OVF_CAP * 8;
        p = align_up(p, 16);
        uint32* xb      = (uint32*)p;         p += (size_t)n * 128;
        int*    slots   = (int*)p;
        const size_t fixed = (size_t)(p - (char*)d_ws);
        int C = 0;
        if (ws_size > fixed) {
            size_t c_avail = (ws_size - fixed) / ((size_t)n * 4);
            C = (c_avail > 32) ? 32 : (int)c_avail;
        }
        if (C < 1) return;  // ws too small for anything sane
        hipMemsetAsync(deg, 0, (size_t)n * 4 + 4, stream);
        k_prep<<<(E + 255) / 256, 256, 0, stream>>>(
            (const float2*)x, xb, row, col, deg, slots, ovf, ovf_cnt,
            nhalf, E, C);
        k_winv<<<(n + 255) / 256, 256, 0, stream>>>(deg, winv, n);
        const long long tt = (long long)n * 64;
        const int blocks = (int)((tt + 255) / 256);
        k_gather4d<<<blocks, 256, 0, stream>>>(xb, (const float4*)x, deg, winv,
                                               slots, alpha, res_scale,
                                               (float4*)out, n, C);
        k_ovf<<<64, 256, 0, stream>>>(ovf, ovf_cnt, x, winv, alpha, out);
    }
}